// Round 18
// baseline (2000.754 us; speedup 1.0000x reference)
//
#include <hip/hip_runtime.h>
#include <hip/hip_bf16.h>

// EntropyResidualBlock: y1 = prelu(maskconv(x,w1)+b1); y2 = prelu(maskconv(y1,w2)+b2); out = y2 + x
// 13 live taps. Implicit GEMM with mfma_f32_32x32x16_bf16.
//   conv1: D[p][o] = sum X[p+d(t)][i]*W1[t][i][o]  (A=X,B=W);  conv2: D[o][p] (A=W,B=Y).
// Layouts: X/Y packed [n][kc=24 x 16ch][h+4][w+4][16] bf16 (halo-padded);
//          W packed [t][kc][o][16] bf16 (masked).
// Round-18: deterministic role-split (m201's T3 mechanism). R17's two co-resident
// 256-thread blocks collide their MFMA bursts (emergent phase, 45% true MFMA-busy,
// ~600 idle cyc/step-pair). Merge them into ONE 512-thread block: group A (waves
// 0-3, rows h0..h0+1) and group B (waves 4-7, rows h0+2..h0+3), each an exact
// copy of R17's verified pipeline (own 2x36.9KB LDS dbuf, own xg ring-4 / wb
// ring-2 / staging). Inner loop: 26 clusters x {bar; A: 8 MFMA + own loads;
// bar; B: 8 MFMA + own loads} -> exactly one group issues MFMA per phase, bursts
// pack back-to-back by construction. Barriers unconditional top-level (counts
// match on all paths; live12 skips MFMAs only). Dbuf still fenced by
// __syncthreads. Registers per wave unchanged (128+128 = 2 waves/SIMD, full pool).

#define C_CH 384
#define HH   256
#define WWD  512
#define NN   2
#define NKC  24                    // 16-channel chunks
#define PR   260
#define PC   516
#define ICS16 (PR * PC * 16)       // shorts per (n,kc) plane = 2,146,560
#define TCOLS 144
#define PLANE_SH (4 * TCOLS * 16)  // 9216 shorts per hf sub-plane in LDS
#define TSH (2 * PLANE_SH)         // 18432 shorts = 36,864 B per buffer
#define TSTRIDE (NKC * C_CH * 16)  // 147456 shorts: t -> t+1 in wp
#define ICSTRIDE (2 * C_CH * 16)   // 12288 shorts: ic -> ic+1 (kc += 2)

typedef __attribute__((ext_vector_type(8)))  short short8;
typedef __attribute__((ext_vector_type(16))) float f32x16;

typedef const __attribute__((address_space(1))) void* gas_t;
typedef __attribute__((address_space(3))) void* las_t;

__device__ inline unsigned short f2bf(float f) {
    union { float f; unsigned int u; } v; v.f = f;
    unsigned int r = v.u + 0x7FFFu + ((v.u >> 16) & 1u);
    return (unsigned short)(r >> 16);
}

// ---------------- weights -> bf16 wp[t][kc][o][16], masked ----------------
__global__ __launch_bounds__(256) void k_prepack(const float* __restrict__ w1, const float* __restrict__ w2,
                                                 unsigned short* __restrict__ wp1, unsigned short* __restrict__ wp2) {
    int idx = blockIdx.x * 256 + threadIdx.x;
    const int TOT = 13 * NKC * C_CH * 16;
    if (idx >= TOT) return;
    int iq = idx & 15;
    int o  = (idx >> 4) % C_CH;
    int kc = (idx / (16 * C_CH)) % NKC;
    int t  = idx / (16 * C_CH * NKC);
    int i  = kc * 16 + iq;
    int kh = t < 5 ? 0 : (t < 10 ? 1 : 2);
    int kw = t < 5 ? t : (t < 10 ? t - 5 : t - 10);
    bool keep = (t != 12) || ((i / 24) <= (o / 24));
    int src = ((o * C_CH + i) * 5 + kh) * 5 + kw;
    wp1[idx] = keep ? f2bf(w1[src]) : (unsigned short)0;
    wp2[idx] = keep ? f2bf(w2[src]) : (unsigned short)0;
}

// ---------------- zero the halo borders of both packed buffers ----------------
__global__ __launch_bounds__(256) void k_zero_halo(unsigned short* __restrict__ a, unsigned short* __restrict__ b) {
    int plane = blockIdx.x;            // 0..47 (n*NKC+kc)
    const short8 z = (short8){0,0,0,0,0,0,0,0};
    for (int bi = 0; bi < 2; ++bi) {
        unsigned short* p = (bi ? b : a) + (size_t)plane * ICS16;
        for (int i = threadIdx.x; i < 4128; i += 256) {
            int r4 = i / 1032;
            int rem = i - r4 * 1032;
            int row = r4 < 2 ? r4 : 254 + r4;
            *(short8*)&p[row * (PC * 16) + rem * 8] = z;
        }
        for (int i = threadIdx.x; i < 2048; i += 256) {
            int row = 2 + (i >> 3);
            int j = i & 7;
            int col = (j < 4) ? (j >> 1) : (512 + (j >> 1));
            int q = j & 1;
            *(short8*)&p[(row * PC + col) * 16 + q * 8] = z;
        }
    }
}

// ---------------- x NCHW fp32 -> padded 16ch-chunked bf16 ----------------
__global__ __launch_bounds__(256) void k_repack_x(const float* __restrict__ x, unsigned short* __restrict__ xc) {
    int bid = blockIdx.x;              // 4096 blocks: 64 w x 384 c for one (n,h)
    int w0 = (bid & 7) << 6;
    int h  = (bid >> 3) & 255;
    int n  = bid >> 11;
    int wi = threadIdx.x & 63;
    int cq = threadIdx.x >> 6;         // 0..3 (8 channels each)
    int w  = w0 + wi;
    int inb = n * C_CH * HH * WWD + h * WWD + w;
    for (int cc = 0; cc < 12; ++cc) {
        int c0 = cc * 32 + cq * 8;
        short8 outv;
        #pragma unroll
        for (int k = 0; k < 8; ++k) {
            float f = x[inb + (c0 + k) * (HH * WWD)];
            outv[k] = (short)f2bf(f);
        }
        int kc = cc * 2 + (cq >> 1);
        int oidx = (n * NKC + kc) * ICS16 + ((h + 2) * PC + (w + 2)) * 16 + (cq & 1) * 8;
        *(short8*)&xc[oidx] = outv;
    }
}

// ---------------- masked conv via 32x32x16 MFMA ----------------
// grid 1536 = 8 xcd x 192; 512 threads / 8 waves: grp=wv>>2 (row-pair), wvg=wv&3.
template<int SECOND>
__global__ __launch_bounds__(512, 1) void k_conv(const unsigned short* __restrict__ in,   // packed
                                                 const unsigned short* __restrict__ wp,
                                                 const float* __restrict__ bias,
                                                 const float* __restrict__ alpha,
                                                 const float* __restrict__ xres,
                                                 void* __restrict__ outp) {
    __shared__ __align__(16) unsigned short Xs[2][2][TSH];   // [grp][buf], 147,456 B

    // XCD-contiguous; ob innermost (192 = 3*64 ✓)
    int bid0 = blockIdx.x;
    int xcd = bid0 & 7;
    int j0  = bid0 >> 3;                 // 0..191
    int tile = xcd * 64 + j0 / 3;        // 0..511
    int ob   = j0 % 3;
    int n    = tile >> 8;
    int hq   = (tile >> 2) & 63;
    int wseg = tile & 3;
    int w0 = wseg << 7, o0 = ob << 7;

    int tid = threadIdx.x;
    int lane = tid & 63;
    int wv = tid >> 6;                   // 0..7
    int grp = wv >> 2;                   // 0 = rows h0b..h0b+1, 1 = rows h0b+2..h0b+3
    int wvg = wv & 3;
    int wr = wvg >> 1, wc = wvg & 1;
    int lo5 = lane & 31, hi = lane >> 5;
    int h0 = (hq << 2) + grp * 2;        // group's output row base

    // staging: 36 wave-issues per group buffer, 9 per wave; per-lane global offsets
    int goff[9];
    #pragma unroll
    for (int it = 0; it < 9; ++it) {
        int k = wvg * 9 + it;
        int plane = k / 18;
        int s = (k % 18) * 64 + lane;
        int r = s / 288;
        int rem = s - r * 288;
        int col = rem >> 1, h16 = rem & 1;
        goff[it] = plane * ICS16 + ((h0 + r) * PC + (w0 + col)) * 16 + h16 * 8;
    }

    f32x16 acc[4][2];
    #pragma unroll
    for (int pt = 0; pt < 4; ++pt)
        #pragma unroll
        for (int ot = 0; ot < 2; ++ot)
            #pragma unroll
            for (int r = 0; r < 16; ++r) acc[pt][ot][r] = 0.f;

    const unsigned short* gbase_n = in + (size_t)n * NKC * ICS16;

    // ---- strength-reduced bases (R11) ----
    const int xlane = wr * (TCOLS * 16) + lo5 * 16 + hi * 8;
    const unsigned short* wpb = wp + (size_t)(o0 + wc * 64) * 16;
    const int wlane = lo5 * 16 + hi * 8;
    int woff0 = 0;            // slot0 scalar offset (shorts)
    int woff1 = C_CH * 16;    // slot1: hf=1 -> kc=1

    const int KH[13] = {0,0,0,0,0,1,1,1,1,1,2,2,2};
    const int KW[13] = {0,1,2,3,4,0,1,2,3,4,0,1,2};

// granule u = 2*step + phalf; step = (t,hf); granule covers pt pair {0,1} or {2,3}
#define LOAD_XG(dst, u) do {                                              \
        const int s_ = (u) >> 1, ph_ = (u) & 1;                           \
        const int t_ = s_ >> 1, hf_ = s_ & 1;                             \
        const int c0_ = hf_ * PLANE_SH + KH[t_] * (TCOLS * 16)            \
                      + KW[t_] * 16 + ph_ * 1024;                         \
        (dst)[0] = *(const short8*)&xsp[xlane + c0_];                     \
        (dst)[1] = *(const short8*)&xsp[xlane + c0_ + 512];               \
    } while (0)

#define LOAD_WB(dst, woff) do {                                           \
        (dst)[0] = *(const short8*)&wpb[(woff) + wlane];                  \
        (dst)[1] = *(const short8*)&wpb[(woff) + wlane + 512];            \
    } while (0)

// one granule g: 4 MFMA; pt-pair from g&1, xg slot g&3, wb slot (g>>1)&1
#define GRANULE(g) do {                                                   \
        const int pt0_ = ((g) & 1) * 2;                                   \
        _Pragma("unroll")                                                 \
        for (int pi = 0; pi < 2; ++pi)                                    \
            _Pragma("unroll")                                             \
            for (int ot = 0; ot < 2; ++ot) {                              \
                if (SECOND)                                               \
                    acc[pt0_ + pi][ot] = __builtin_amdgcn_mfma_f32_32x32x16_bf16( \
                        wb[((g) >> 1) & 1][ot], xg[(g) & 3][pi], acc[pt0_ + pi][ot], 0, 0, 0); \
                else                                                      \
                    acc[pt0_ + pi][ot] = __builtin_amdgcn_mfma_f32_32x32x16_bf16( \
                        xg[(g) & 3][pi], wb[((g) >> 1) & 1][ot], acc[pt0_ + pi][ot], 0, 0, 0); \
            }                                                             \
    } while (0)

// own-phase work for cluster c: 8 MFMA, then own xg prefetch (c+2) + wb refill
#define PHASE_WORK(c) do {                                                \
        __builtin_amdgcn_s_setprio(1);                                    \
        if ((c) < 24 || live12) { GRANULE(2*(c)); GRANULE(2*(c)+1); }     \
        __builtin_amdgcn_s_setprio(0);                                    \
        if ((c) < 24) {                                                   \
            LOAD_XG(xg[(2*(c)+4) & 3], 2*(c)+4);                          \
            LOAD_XG(xg[(2*(c)+5) & 3], 2*(c)+5);                          \
        }                                                                 \
        if ((c) + 2 < 26) {                                               \
            if (((c) & 1) == 0) { woff0 += TSTRIDE; LOAD_WB(wb[0], woff0); } \
            else                { woff1 += TSTRIDE; LOAD_WB(wb[1], woff1); } \
        } else {                                                          \
            if (((c) & 1) == 0) { woff0 += ICSTRIDE - 12 * TSTRIDE; LOAD_WB(wb[0], woff0); } \
            else                { woff1 += ICSTRIDE - 12 * TSTRIDE; LOAD_WB(wb[1], woff1); } \
        }                                                                 \
    } while (0)

    short8 wb[2][2];
    // wb for (ic=0, u=0,1) issued FIRST: ahead of all staging in the vmcnt queue
    LOAD_WB(wb[0], woff0);
    LOAD_WB(wb[1], woff1);

    // prologue: stage ic=0 into buf 0 (each group its own tile)
    #pragma unroll
    for (int it = 0; it < 9; ++it)
        __builtin_amdgcn_global_load_lds((gas_t)(gbase_n + goff[it]),
                                         (las_t)&Xs[grp][0][(wvg * 9 + it) * 512], 16, 0, 0);
    __syncthreads();

    for (int ic = 0; ic < 12; ++ic) {
        const unsigned short* xsp = &Xs[grp][ic & 1][0];
        // stage next ic into other buffer
        if (ic < 11) {
            const unsigned short* gb = gbase_n + (size_t)(ic + 1) * 2 * ICS16;
            #pragma unroll
            for (int it = 0; it < 9; ++it)
                __builtin_amdgcn_global_load_lds((gas_t)(gb + goff[it]),
                                                 (las_t)&Xs[grp][(ic & 1) ^ 1][(wvg * 9 + it) * 512], 16, 0, 0);
        }

        // dead tap-12 (clusters 24,25): ob- and ic-uniform => same for all 8 waves
        const bool live12 = !((ob == 0 && ic >= 5) || (ob == 1 && ic >= 9));

        // xg ring-4: ic-top loads granules 0..3 (clusters 0,1)
        short8 xg[4][2];
        LOAD_XG(xg[0], 0);
        LOAD_XG(xg[1], 1);
        LOAD_XG(xg[2], 2);
        LOAD_XG(xg[3], 3);

        // 26 clusters; per cluster: phase1 = group0 computes, phase2 = group1.
        // Exactly one group issues MFMA per phase -> bursts pack back-to-back.
        // Barriers unconditional + top-level: all 8 waves, identical count.
        #pragma unroll
        for (int c = 0; c < 26; ++c) {
            __builtin_amdgcn_s_barrier();
            if (grp == 0) PHASE_WORK(c);
            __builtin_amdgcn_s_barrier();
            if (grp == 1) PHASE_WORK(c);
        }
        __syncthreads();
    }
#undef LOAD_XG
#undef LOAD_WB
#undef GRANULE
#undef PHASE_WORK

    int h = h0 + wr;
    if (!SECOND) {
        // D[p][o]: p = pt*32 + (reg&3)+8*(reg>>2)+4*hi ; o = o0+wc*64+ot*32+lo5
        unsigned short* y = (unsigned short*)outp;
        #pragma unroll
        for (int ot = 0; ot < 2; ++ot) {
            int o = o0 + wc * 64 + ot * 32 + lo5;
            float bo = bias[o], ao = alpha[o];
            int kc = o >> 4;
            int o15 = o & 15;
            size_t base = (size_t)(n * NKC + kc) * ICS16 + ((h + 2) * PC + (w0 + 2)) * 16 + o15;
            #pragma unroll
            for (int pt = 0; pt < 4; ++pt) {
                #pragma unroll
                for (int reg = 0; reg < 16; ++reg) {
                    int p = pt * 32 + (reg & 3) + 8 * (reg >> 2) + 4 * hi;
                    float v = acc[pt][ot][reg] + bo;
                    v = v >= 0.f ? v : ao * v;
                    y[base + (size_t)p * 16] = f2bf(v);
                }
            }
        }
    } else {
        // D[o][p]: o = o0+wc*64+ot*32+(reg&3)+8*(reg>>2)+4*hi ; w = w0+pt*32+lo5
        float* outf = (float*)outp;
        #pragma unroll
        for (int ot = 0; ot < 2; ++ot) {
            #pragma unroll
            for (int reg = 0; reg < 16; ++reg) {
                int o = o0 + wc * 64 + ot * 32 + (reg & 3) + 8 * (reg >> 2) + 4 * hi;
                float bo = bias[o], ao = alpha[o];
                #pragma unroll
                for (int pt = 0; pt < 4; ++pt) {
                    int w = w0 + pt * 32 + lo5;
                    float v = acc[pt][ot][reg] + bo;
                    v = v >= 0.f ? v : ao * v;
                    size_t idx = (size_t)((n * C_CH + o) * HH + h) * WWD + w;
                    outf[idx] = v + xres[idx];
                }
            }
        }
    }
}

extern "C" void kernel_launch(void* const* d_in, const int* in_sizes, int n_in,
                              void* d_out, int out_size, void* d_ws, size_t ws_size,
                              hipStream_t stream) {
    const float* x  = (const float*)d_in[0];
    const float* w1 = (const float*)d_in[1];
    const float* b1 = (const float*)d_in[2];
    const float* a1 = (const float*)d_in[3];
    const float* w2 = (const float*)d_in[4];
    const float* b2 = (const float*)d_in[5];
    const float* a2 = (const float*)d_in[6];

    const size_t PLANE_SHORTS = (size_t)NN * NKC * ICS16;       // 103,034,880 shorts
    unsigned short* xc  = (unsigned short*)d_out;               // 206,069,760 B scratch in d_out
    unsigned short* yb  = (unsigned short*)d_ws;                // 206,069,760 B
    unsigned short* wp1 = yb + PLANE_SHORTS;                    // 3,833,856 B
    unsigned short* wp2 = wp1 + 13 * NKC * C_CH * 16;           // 3,833,856 B

    k_prepack<<<(13 * NKC * C_CH * 16 + 255) / 256, 256, 0, stream>>>(w1, w2, wp1, wp2);
    k_zero_halo<<<NN * NKC, 256, 0, stream>>>(xc, yb);
    k_repack_x<<<NN * HH * (WWD / 64), 256, 0, stream>>>(x, xc);
    k_conv<0><<<1536, 512, 0, stream>>>(xc, wp1, b1, a1, nullptr, (void*)yb);
    k_conv<1><<<1536, 512, 0, stream>>>(yb, wp2, b2, a2, x, (void*)d_out);
}